// Round 3
// baseline (731.529 us; speedup 1.0000x reference)
//
#include <hip/hip_runtime.h>

// HardBinaryVote: votes (63, N) int32 in {0,1}; weights (63,) fp32.
// out[j] = (sum_{v[i][j]==1} w[i]) > (sum_{v[i][j]==0} w[i]) ? 1 : 0  (int32)
//
// R3 = MEASUREMENT ROUND. dur_us includes ~470 us of fixed harness reset
// (ws fill 310 us + input restore ~158 us), and our kernel never appears in
// the top-5 rocprof table (all slots taken by ~310 us fills), so kernel time
// is unobservable directly. This round launches R2's kernel verbatim (A,
// int2/2-samples) followed by an int4/4-samples variant (B) writing the
// identical output.  Since overhead + T_A = 637.0 us (R2 measurement),
//     dur_us(R3) - 637.0 = T_B  exactly.
// Next round strips A and submits the winner alone.
//
// CORRECTNESS-CRITICAL (verified absmax 0.0 in R1/R2): both kernels replicate
// numpy's pairwise_sum for n=63 (8 accumulators over rows 0..55, combine
// ((r0+r1)+(r2+r3))+((r4+r5)+(r6+r7)), then sequential tail rows 56..62) so
// the fp32 sums are BIT-EXACT vs the numpy reference -- the (c1 > c0) sign
// comparison cannot flip on near-ties. Do NOT reassociate / fast-math.

#define NM 63

// ---------------- Kernel A: R2 verbatim (int2, 2 samples/thread) ------------
__global__ __launch_bounds__(256, 4) void hbv_kernel_a(
    const int* __restrict__ votes, const float* __restrict__ wts,
    int* __restrict__ out, int n)
{
    __shared__ float ws[64];
    if (threadIdx.x < NM) ws[threadIdx.x] = wts[threadIdx.x];
    __syncthreads();

    const size_t t  = (size_t)blockIdx.x * blockDim.x + threadIdx.x;
    const size_t j0 = t * 2;
    if (j0 >= (size_t)n) return;

    const size_t row = (size_t)n;

    float r1[8][2], r0[8][2];
#pragma unroll
    for (int k = 0; k < 8; ++k)
#pragma unroll
        for (int s = 0; s < 2; ++s) { r1[k][s] = 0.0f; r0[k][s] = 0.0f; }

#pragma unroll 1
    for (int b = 0; b < 7; ++b) {
        int2 v[8];
#pragma unroll
        for (int k = 0; k < 8; ++k)
            v[k] = *(const int2*)(votes + (size_t)(8 * b + k) * row + j0);
#pragma unroll
        for (int k = 0; k < 8; ++k) {
            const float wi = ws[8 * b + k];
            r1[k][0] += (v[k].x != 0) ? wi : 0.0f;
            r0[k][0] += (v[k].x == 0) ? wi : 0.0f;
            r1[k][1] += (v[k].y != 0) ? wi : 0.0f;
            r0[k][1] += (v[k].y == 0) ? wi : 0.0f;
        }
    }

    float c1[2], c0[2];
#pragma unroll
    for (int s = 0; s < 2; ++s) {
        c1[s] = ((r1[0][s] + r1[1][s]) + (r1[2][s] + r1[3][s]))
              + ((r1[4][s] + r1[5][s]) + (r1[6][s] + r1[7][s]));
        c0[s] = ((r0[0][s] + r0[1][s]) + (r0[2][s] + r0[3][s]))
              + ((r0[4][s] + r0[5][s]) + (r0[6][s] + r0[7][s]));
    }

    {
        int2 v[7];
#pragma unroll
        for (int i = 0; i < 7; ++i)
            v[i] = *(const int2*)(votes + (size_t)(56 + i) * row + j0);
#pragma unroll
        for (int i = 0; i < 7; ++i) {
            const float wi = ws[56 + i];
            c1[0] += (v[i].x != 0) ? wi : 0.0f;
            c0[0] += (v[i].x == 0) ? wi : 0.0f;
            c1[1] += (v[i].y != 0) ? wi : 0.0f;
            c0[1] += (v[i].y == 0) ? wi : 0.0f;
        }
    }

    int2 res;
    res.x = (c1[0] > c0[0]) ? 1 : 0;
    res.y = (c1[1] > c0[1]) ? 1 : 0;
    *(int2*)(out + j0) = res;
}

// ---------------- Kernel B: int4, 4 samples/thread ------------------------
__global__ __launch_bounds__(256, 4) void hbv_kernel_b(
    const int* __restrict__ votes, const float* __restrict__ wts,
    int* __restrict__ out, int n)
{
    __shared__ float ws[64];
    if (threadIdx.x < NM) ws[threadIdx.x] = wts[threadIdx.x];
    __syncthreads();

    const size_t t  = (size_t)blockIdx.x * blockDim.x + threadIdx.x;
    const size_t j0 = t * 4;
    if (j0 >= (size_t)n) return;

    const size_t row = (size_t)n;

    float r1[8][4], r0[8][4];
#pragma unroll
    for (int k = 0; k < 8; ++k)
#pragma unroll
        for (int s = 0; s < 4; ++s) { r1[k][s] = 0.0f; r0[k][s] = 0.0f; }

    // Rows 0..55 in blocks of 8; unroll 1 keeps 8 int4 loads in flight.
#pragma unroll 1
    for (int b = 0; b < 7; ++b) {
        int4 v[8];
#pragma unroll
        for (int k = 0; k < 8; ++k)
            v[k] = *(const int4*)(votes + (size_t)(8 * b + k) * row + j0);
#pragma unroll
        for (int k = 0; k < 8; ++k) {
            const float wi = ws[8 * b + k];
            const int vv[4] = {v[k].x, v[k].y, v[k].z, v[k].w};
#pragma unroll
            for (int s = 0; s < 4; ++s) {
                r1[k][s] += (vv[s] != 0) ? wi : 0.0f;
                r0[k][s] += (vv[s] == 0) ? wi : 0.0f;
            }
        }
    }

    float c1[4], c0[4];
#pragma unroll
    for (int s = 0; s < 4; ++s) {
        c1[s] = ((r1[0][s] + r1[1][s]) + (r1[2][s] + r1[3][s]))
              + ((r1[4][s] + r1[5][s]) + (r1[6][s] + r1[7][s]));
        c0[s] = ((r0[0][s] + r0[1][s]) + (r0[2][s] + r0[3][s]))
              + ((r0[4][s] + r0[5][s]) + (r0[6][s] + r0[7][s]));
    }

    {
        int4 v[7];
#pragma unroll
        for (int i = 0; i < 7; ++i)
            v[i] = *(const int4*)(votes + (size_t)(56 + i) * row + j0);
#pragma unroll
        for (int i = 0; i < 7; ++i) {
            const float wi = ws[56 + i];
            const int vv[4] = {v[i].x, v[i].y, v[i].z, v[i].w};
#pragma unroll
            for (int s = 0; s < 4; ++s) {
                c1[s] += (vv[s] != 0) ? wi : 0.0f;
                c0[s] += (vv[s] == 0) ? wi : 0.0f;
            }
        }
    }

    int4 res;
    res.x = (c1[0] > c0[0]) ? 1 : 0;
    res.y = (c1[1] > c0[1]) ? 1 : 0;
    res.z = (c1[2] > c0[2]) ? 1 : 0;
    res.w = (c1[3] > c0[3]) ? 1 : 0;
    *(int4*)(out + j0) = res;
}

extern "C" void kernel_launch(void* const* d_in, const int* in_sizes, int n_in,
                              void* d_out, int out_size, void* d_ws, size_t ws_size,
                              hipStream_t stream)
{
    const int*   votes = (const int*)d_in[0];
    const float* wts   = (const float*)d_in[1];
    int*         out   = (int*)d_out;
    const int n = out_size;                 // N_SAMPLES = 2,000,000

    const int threads = 256;

    // Pass A (R2 verbatim): overhead + T_A = 637.0 us known from R2.
    {
        const int nthreads = (n + 1) / 2;
        const int blocks   = (nthreads + threads - 1) / threads;
        hipLaunchKernelGGL(hbv_kernel_a, dim3(blocks), dim3(threads), 0, stream,
                           votes, wts, out, n);
    }
    // Pass B (int4 candidate): overwrites out with identical values.
    // dur_us(R3) - 637.0 = T_B.
    {
        const int nthreads = (n + 3) / 4;
        const int blocks   = (nthreads + threads - 1) / threads;
        hipLaunchKernelGGL(hbv_kernel_b, dim3(blocks), dim3(threads), 0, stream,
                           votes, wts, out, n);
    }
}

// Round 4
// 639.086 us; speedup vs baseline: 1.1446x; 1.1446x over previous
//
#include <hip/hip_runtime.h>

// HardBinaryVote: votes (63, N) int32 in {0,1}; weights (63,) fp32.
// out[j] = (sum_{v[i][j]==1} w[i]) > (sum_{v[i][j]==0} w[i]) ? 1 : 0  (int32)
//
// MEASUREMENT LEDGER (exact, from differential rounds):
//   R2: OH + T_A = 636.9 us   (A = int2/2-sample kernel; OH = harness reset,
//                              ~310 us ws-fill + ~160 us input restore)
//   R3: OH + T_A + T_B = 731.5 us  =>  T_B = 94.6 us exactly
//       (B = int4/4-sample) => 512 MB / 94.6 us = 5.41 TB/s, ~85% of the
//       6.4-6.5 TB/s the harness's own fillBuffer dispatches demonstrate.
// Little's law says latency-hiding is NOT the limiter (need ~9.2 KB/CU in
// flight, B holds ~128 KB), VALU ~11% busy -> residual gap is launch/tail
// effects + DRAM pattern ceiling. R4 = C alone, C = B + exact-fit grid-stride
// (1024 blocks = 4/CU) to attack the tail; dropping kernel A removes ~T_A
// from scored dur_us. Next round, C+C duplicate gives T_C = D5 - D4 exactly.
//
// CORRECTNESS-CRITICAL (absmax 0.0 in R1-R3): replicate numpy's pairwise_sum
// for n=63 — 8 accumulators over rows 0..55 (r[k] sums rows k, k+8, ..,
// k+48), combine ((r0+r1)+(r2+r3))+((r4+r5)+(r6+r7)), then sequential tail
// rows 56..62 — so c1/c0 are BIT-EXACT vs the reference and the (c1 > c0)
// sign comparison cannot flip on near-ties. Do NOT reassociate / fast-math.

#define NM 63

__global__ __launch_bounds__(256, 4) void hbv_kernel_c(
    const int* __restrict__ votes, const float* __restrict__ wts,
    int* __restrict__ out, int n)
{
    __shared__ float ws[64];
    if (threadIdx.x < NM) ws[threadIdx.x] = wts[threadIdx.x];
    __syncthreads();

    const size_t nthreads = (size_t)gridDim.x * blockDim.x;
    const size_t tid      = (size_t)blockIdx.x * blockDim.x + threadIdx.x;
    const size_t nchunks  = (size_t)(n >> 2);        // n divisible by 4
    const size_t row      = (size_t)n;

    // Grid-stride over 4-sample chunks: 1024 blocks x 256 thr = 262144
    // threads, ~1.9 chunks each. Lane-contiguous int4 => fully coalesced.
#pragma unroll 1
    for (size_t c = tid; c < nchunks; c += nthreads) {
        const size_t j0 = c * 4;

        // numpy pairwise accumulators
        float r1[8][4], r0[8][4];
#pragma unroll
        for (int k = 0; k < 8; ++k)
#pragma unroll
            for (int s = 0; s < 4; ++s) { r1[k][s] = 0.0f; r0[k][s] = 0.0f; }

        // Rows 0..55 in blocks of 8; unroll 1 keeps 8 int4 loads in flight.
#pragma unroll 1
        for (int b = 0; b < 7; ++b) {
            int4 v[8];
#pragma unroll
            for (int k = 0; k < 8; ++k)
                v[k] = *(const int4*)(votes + (size_t)(8 * b + k) * row + j0);
#pragma unroll
            for (int k = 0; k < 8; ++k) {
                const float wi = ws[8 * b + k];
                const int vv[4] = {v[k].x, v[k].y, v[k].z, v[k].w};
#pragma unroll
                for (int s = 0; s < 4; ++s) {
                    r1[k][s] += (vv[s] != 0) ? wi : 0.0f;
                    r0[k][s] += (vv[s] == 0) ? wi : 0.0f;
                }
            }
        }

        // numpy combine order
        float c1[4], c0[4];
#pragma unroll
        for (int s = 0; s < 4; ++s) {
            c1[s] = ((r1[0][s] + r1[1][s]) + (r1[2][s] + r1[3][s]))
                  + ((r1[4][s] + r1[5][s]) + (r1[6][s] + r1[7][s]));
            c0[s] = ((r0[0][s] + r0[1][s]) + (r0[2][s] + r0[3][s]))
                  + ((r0[4][s] + r0[5][s]) + (r0[6][s] + r0[7][s]));
        }

        // tail rows 56..62, sequential (numpy tail loop)
        {
            int4 v[7];
#pragma unroll
            for (int i = 0; i < 7; ++i)
                v[i] = *(const int4*)(votes + (size_t)(56 + i) * row + j0);
#pragma unroll
            for (int i = 0; i < 7; ++i) {
                const float wi = ws[56 + i];
                const int vv[4] = {v[i].x, v[i].y, v[i].z, v[i].w};
#pragma unroll
                for (int s = 0; s < 4; ++s) {
                    c1[s] += (vv[s] != 0) ? wi : 0.0f;
                    c0[s] += (vv[s] == 0) ? wi : 0.0f;
                }
            }
        }

        int4 res;
        res.x = (c1[0] > c0[0]) ? 1 : 0;
        res.y = (c1[1] > c0[1]) ? 1 : 0;
        res.z = (c1[2] > c0[2]) ? 1 : 0;
        res.w = (c1[3] > c0[3]) ? 1 : 0;
        *(int4*)(out + j0) = res;
    }
}

extern "C" void kernel_launch(void* const* d_in, const int* in_sizes, int n_in,
                              void* d_out, int out_size, void* d_ws, size_t ws_size,
                              hipStream_t stream)
{
    const int*   votes = (const int*)d_in[0];
    const float* wts   = (const float*)d_in[1];
    int*         out   = (int*)d_out;
    const int n = out_size;                 // N_SAMPLES = 2,000,000

    // Exact-fit grid: 256 CUs x 4 blocks/CU resident (launch_bounds(256,4)).
    const int threads = 256;
    const int blocks  = 1024;

    hipLaunchKernelGGL(hbv_kernel_c, dim3(blocks), dim3(threads), 0, stream,
                       votes, wts, out, n);
}